// Round 2
// baseline (236.254 us; speedup 1.0000x reference)
//
#include <hip/hip_runtime.h>
#include <stdint.h>
#include <stddef.h>

#define DIM   256
#define NH    8
#define HD    32
#define BATCH 16
#define NTOK  4096   // 64*64

typedef __attribute__((ext_vector_type(8))) short short8;
typedef __attribute__((ext_vector_type(4))) float f32x4;

__device__ __forceinline__ unsigned short f2bf(float x){
  unsigned u = __float_as_uint(x);
  u += 0x7fffu + ((u >> 16) & 1u);       // RNE
  return (unsigned short)(u >> 16);
}
__device__ __forceinline__ float elu1(float v){
  return (v > 0.f) ? (v + 1.f) : __expf(v);
}
// async global->LDS, 16B per lane. lds dest = wave-uniform base + lane*16.
__device__ __forceinline__ void gload_lds16(const void* g, void* lds){
  __builtin_amdgcn_global_load_lds(
      (const __attribute__((address_space(1))) unsigned int*)g,
      (__attribute__((address_space(3))) unsigned int*)lds, 16, 0, 0);
}

// ---------------- P1: x [b][c][n] f32 -> x_t [b][n][c] bf16 ----------------
__global__ __launch_bounds__(256) void k_transpose_x(const float* __restrict__ x,
                                                     unsigned short* __restrict__ xt){
  __shared__ float tile[64][65];
  const int b = blockIdx.z, c0 = blockIdx.y * 64, n0 = blockIdx.x * 64;
  const float* xb = x + (size_t)b * DIM * NTOK;
  const int t = threadIdx.x;
  #pragma unroll
  for (int p = 0; p < 4; p++){
    int idx = t + p * 256;
    int row = idx >> 4;
    int col = (idx & 15) << 2;
    float4 v = *(const float4*)(xb + (size_t)(c0 + row) * NTOK + n0 + col);
    tile[row][col] = v.x; tile[row][col+1] = v.y; tile[row][col+2] = v.z; tile[row][col+3] = v.w;
  }
  __syncthreads();
  unsigned short* xtb = xt + (size_t)b * NTOK * DIM;
  #pragma unroll
  for (int p = 0; p < 4; p++){
    int idx = t + p * 256;
    int nl = idx >> 4;
    int cl = (idx & 15) << 2;
    ushort4 o;
    o.x = f2bf(tile[cl+0][nl]); o.y = f2bf(tile[cl+1][nl]);
    o.z = f2bf(tile[cl+2][nl]); o.w = f2bf(tile[cl+3][nl]);
    *(ushort4*)(xtb + (size_t)(n0 + nl) * DIM + c0 + cl) = o;
  }
}

// ---------------- P2: convert Wqkv to bf16, PERMUTED row layout ----------------
// dest rows: [0..255]=q. Then 4 tiles of 128: tile p = [k heads 2p,2p+1 | v heads 2p,2p+1]
__global__ __launch_bounds__(256) void k_convert_w(const float* __restrict__ wqkv,
                                                   unsigned short* __restrict__ wq_bf){
  int i = blockIdx.x * 256 + threadIdx.x;  // 49152 threads: 768 rows x 64 groups of 4c
  int row = i >> 6;
  int c4 = (i & 63) * 4;
  int dst;
  if (row < 256)      dst = row;
  else if (row < 512){ int p = (row - 256) >> 6; int s = (row - 256) & 63; dst = 256 + p*128 + s; }
  else               { int p = (row - 512) >> 6; int s = (row - 512) & 63; dst = 256 + p*128 + 64 + s; }
  float4 v = *(const float4*)(wqkv + (size_t)row * DIM + c4);
  ushort4 o = { f2bf(v.x), f2bf(v.y), f2bf(v.z), f2bf(v.w) };
  *(ushort4*)(wq_bf + (size_t)dst * DIM + c4) = o;
}

// ---------------- K1: persistent qkv GEMM — W-tile in registers, counted-vmcnt pipeline ----------------
// 1536 blocks = 6 o-tiles x 256 chunks. chunk = (b, nt2); block processes pairs nt = nt2*2 + {0,1}.
// Per pair: 4 K-steps of 64. B staged via global_load_lds into 2x16KB dbuf; A (W rows) held in VGPRs
// (a_reg: 64 VGPR/lane). Steady state never drains vmcnt to 0: depth-2 prefetch, s_waitcnt vmcnt(2)
// + raw s_barrier (m201 pattern). Epilogue bounce lives in its own LDS region so in-flight stages for
// the next pair keep flying during the epilogue. kv partials accumulate in registers across the 2
// pairs -> one kvp write per block (16 partials per (b,h) instead of 32).
__global__ __launch_bounds__(512, 4) void k_qkv6(const unsigned short* __restrict__ wbf,
                                                 const unsigned short* __restrict__ xt,
                                                 unsigned short* __restrict__ qn,
                                                 float* __restrict__ kvp){
  __shared__ __align__(16) unsigned short sh[33792];  // 32KB staging (2x 8192 u16) + 34KB bounce
  unsigned short* bsh = sh + 16384;                    // bounce: 128 x 136 u16
  const int t = threadIdx.x;
  const int w = t >> 6, l = t & 63;
  const int t16 = l & 15, quad = l >> 4;
  const int wm = w >> 1, wn = w & 1;     // wm 0..3 (o-quarter), wn 0..1 (n-half)
  // swizzle: 6 o-tiles sharing one chunk land on one XCD (48-bid window, bid%8 const per chunk)
  const int bid = blockIdx.x;
  const int super = bid / 48;            // 0..31
  const int rem = bid - super * 48;
  const int m = rem >> 3, lx = rem & 7;
  const int chunk = super * 8 + lx;      // 0..255
  const int b = chunk >> 4, nt2 = chunk & 15;
  const int o0 = m * 128;
  const bool isQ = (o0 < 256);
  const unsigned short* Bb = xt + ((size_t)b * NTOK + (size_t)nt2 * 256) * DIM;
  const int rowL = (w*16 + t16) * DIM + quad*8;   // per-lane staging offset (A and B share pattern)

  // ---- prologue: A-tile (128o x 256k) -> registers, staged through the B buffers ----
  short8 a_reg[4][2][2];   // [k0-chunk][i over o][kk]
  #pragma unroll
  for (int rp = 0; rp < 2; rp++){
    const unsigned short* srcA = wbf + (size_t)o0 * DIM + rowL + rp*128;
    gload_lds16(srcA,      sh +        (w*2+0)*512);
    gload_lds16(srcA + 32, sh +        (w*2+1)*512);
    gload_lds16(srcA + 64, sh + 8192 + (w*2+0)*512);
    gload_lds16(srcA + 96, sh + 8192 + (w*2+1)*512);
    asm volatile("s_waitcnt vmcnt(0)" ::: "memory");
    __builtin_amdgcn_s_barrier();
    #pragma unroll
    for (int cc = 0; cc < 2; cc++)
      #pragma unroll
      for (int i = 0; i < 2; i++)
        #pragma unroll
        for (int kk = 0; kk < 2; kk++)
          a_reg[rp*2+cc][i][kk] = *(const short8*)(sh + cc*8192 + ((wm*2+i)*2+kk)*512 + l*8);
    asm volatile("s_waitcnt lgkmcnt(0)" ::: "memory");   // reads retired before buffers reused
    __builtin_amdgcn_s_barrier();
  }

  // initial B stages: step0 (pair0,k0=0) -> buf0, step1 (pair0,k0=64) -> buf1
  gload_lds16(Bb + rowL,      sh +        (w*2+0)*512);
  gload_lds16(Bb + rowL + 32, sh +        (w*2+1)*512);
  gload_lds16(Bb + rowL + 64, sh + 8192 + (w*2+0)*512);
  gload_lds16(Bb + rowL + 96, sh + 8192 + (w*2+1)*512);

  f32x4 acc[2][4];
  #pragma unroll
  for (int i = 0; i < 2; i++)
    #pragma unroll
    for (int j = 0; j < 4; j++){ acc[i][j][0]=0.f; acc[i][j][1]=0.f; acc[i][j][2]=0.f; acc[i][j][3]=0.f; }
  f32x4 kvacc;
  kvacc[0]=0.f; kvacc[1]=0.f; kvacc[2]=0.f; kvacc[3]=0.f;

  // ---- main pipeline: 8 steps = 2 pairs x 4 K-steps, depth-2 prefetch ----
  #pragma unroll
  for (int s = 0; s < 8; s++){
    if (s < 7) { asm volatile("s_waitcnt vmcnt(2)" ::: "memory"); }  // own STAGE(s+1) may stay in flight
    else       { asm volatile("s_waitcnt vmcnt(0)" ::: "memory"); }
    __builtin_amdgcn_s_barrier();                                    // all waves' STAGE(s) complete
    const unsigned short* bufc = sh + (s & 1) * 8192;
    #pragma unroll
    for (int kk = 0; kk < 2; kk++){
      short8 bb[4];
      #pragma unroll
      for (int j = 0; j < 4; j++) bb[j] = *(const short8*)(bufc + ((wn*4+j)*2+kk)*512 + l*8);
      #pragma unroll
      for (int i = 0; i < 2; i++)
        #pragma unroll
        for (int j = 0; j < 4; j++)
          acc[i][j] = __builtin_amdgcn_mfma_f32_16x16x32_bf16(a_reg[s&3][i][kk], bb[j], acc[i][j], 0, 0, 0);
    }
    __builtin_amdgcn_s_barrier();       // all waves consumed buf[s&1] (MFMA forces lgkm wait)
    if (s < 6){                          // prefetch step s+2 into the buffer just freed
      const int s2 = s + 2;
      const unsigned short* src = Bb + (size_t)((s2 >> 2) * 128) * DIM + rowL + (s2 & 3) * 64;
      unsigned short* db = sh + (s & 1) * 8192;
      gload_lds16(src,      db + (w*2+0)*512);
      gload_lds16(src + 32, db + (w*2+1)*512);
    }
    if ((s & 3) == 3){
      // ---- per-pair epilogue (overlaps in-flight stages for the next pair) ----
      const int n0 = (nt2*2 + (s >> 2)) * 128;
      if (isQ || wm < 2){
        #pragma unroll
        for (int i = 0; i < 2; i++)
          #pragma unroll
          for (int j = 0; j < 4; j++)
            #pragma unroll
            for (int r = 0; r < 4; r++) acc[i][j][r] = elu1(acc[i][j][r]);
        float sc[4];
        #pragma unroll
        for (int j = 0; j < 4; j++){
          float v = 0.f;
          #pragma unroll
          for (int i = 0; i < 2; i++)
            #pragma unroll
            for (int r = 0; r < 4; r++) v += acc[i][j][r];
          v += __shfl_xor(v, 16);
          v += __shfl_xor(v, 32);
          sc[j] = 1.0f / v;
        }
        #pragma unroll
        for (int i = 0; i < 2; i++)
          #pragma unroll
          for (int j = 0; j < 4; j++){
            float inv = sc[j];
            #pragma unroll
            for (int r = 0; r < 4; r++) acc[i][j][r] *= inv;
          }
      }
      if (isQ){
        // bounce [n_l][o_l] stride 136, packed b64
        #pragma unroll
        for (int i = 0; i < 2; i++)
          #pragma unroll
          for (int j = 0; j < 4; j++){
            int n_l = wn*64 + j*16 + t16;
            int o_l0 = wm*32 + i*16 + quad*4;
            ushort4 pk = { f2bf(acc[i][j][0]), f2bf(acc[i][j][1]),
                           f2bf(acc[i][j][2]), f2bf(acc[i][j][3]) };
            *(ushort4*)(bsh + n_l*136 + o_l0) = pk;
          }
        asm volatile("s_waitcnt lgkmcnt(0)" ::: "memory");   // LDS writes visible (no vmcnt drain!)
        __builtin_amdgcn_s_barrier();
        unsigned short* dst = qn + (size_t)b * NTOK * DIM;
        #pragma unroll
        for (int p2 = 0; p2 < 4; p2++){
          int gg = t + p2 * 512;
          int n_l = gg >> 4, c = gg & 15;
          uint4 v = *(const uint4*)(bsh + n_l*136 + c*8);
          *(uint4*)(dst + (size_t)(n0 + n_l) * DIM + o0 + c*8) = v;
        }
      } else {
        // bounce [o_l][n_l] stride 136 (K-contiguous along n for the kv MFMA)
        #pragma unroll
        for (int i = 0; i < 2; i++)
          #pragma unroll
          for (int j = 0; j < 4; j++){
            int n_l = wn*64 + j*16 + t16;
            #pragma unroll
            for (int r = 0; r < 4; r++){
              int o_l = wm*32 + i*16 + quad*4 + r;
              bsh[o_l*136 + n_l] = f2bf(acc[i][j][r]);
            }
          }
        asm volatile("s_waitcnt lgkmcnt(0)" ::: "memory");
        __builtin_amdgcn_s_barrier();
        // kv partial over this pair's 128 tokens, accumulated in registers across pairs
        const int hl = w >> 2, dh = (w >> 1) & 1, eh = w & 1;
        const unsigned short* kbase = bsh + (hl*32 + dh*16) * 136;        // normalized k rows
        const unsigned short* vbase = bsh + (64 + hl*32 + eh*16) * 136;   // raw v rows
        #pragma unroll
        for (int kk2 = 0; kk2 < 4; kk2++){
          int nn = kk2*32 + quad*8;
          short8 afrag = *(const short8*)(kbase + t16*136 + nn);
          short8 bfrag = *(const short8*)(vbase + t16*136 + nn);
          kvacc = __builtin_amdgcn_mfma_f32_16x16x32_bf16(afrag, bfrag, kvacc, 0, 0, 0);
        }
      }
      if (s == 3){
        #pragma unroll
        for (int i = 0; i < 2; i++)
          #pragma unroll
          for (int j = 0; j < 4; j++){ acc[i][j][0]=0.f; acc[i][j][1]=0.f; acc[i][j][2]=0.f; acc[i][j][3]=0.f; }
      }
    }
  }

  if (!isQ){
    const int pp = (o0 >> 7) - 2;          // head pair 0..3
    const int hl = w >> 2, dh = (w >> 1) & 1, eh = w & 1;
    float* dst = kvp + ((size_t)((b*8 + pp*2 + hl) * 16 + nt2)) * 1024;
    #pragma unroll
    for (int r = 0; r < 4; r++)
      dst[(dh*16 + quad*4 + r)*32 + eh*16 + t16] = kvacc[r];
  }
}

// ---------------- K3: reduce kv partials + fold Wproj: M[b][o][h*32+d] = sum_e Wp[o][h*32+e]*kv[d][e]
__global__ __launch_bounds__(256) void k_M(const float* __restrict__ kvp,
                                           const float* __restrict__ wproj,
                                           unsigned short* __restrict__ M){
  __shared__ float kvL[1024];
  __shared__ float wpL[8192];   // [o][e] 256x32
  const int t = threadIdx.x;
  const int h = blockIdx.x, b = blockIdx.y;
  const float* pbase = kvp + (size_t)((b*8 + h) * 16) * 1024;
  {
    float4 a = {0.f,0.f,0.f,0.f};
    #pragma unroll
    for (int p = 0; p < 16; p++){
      float4 v = *(const float4*)(pbase + (size_t)p*1024 + t*4);
      a.x += v.x; a.y += v.y; a.z += v.z; a.w += v.w;
    }
    *(float4*)(kvL + t*4) = a;
  }
  #pragma unroll
  for (int p = 0; p < 8; p++){
    int idx = t + p * 256;          // float4 index over 256x32
    int o = idx >> 3, e4 = idx & 7;
    *(float4*)(wpL + o*32 + e4*4) = *(const float4*)(wproj + (size_t)o * DIM + h*32 + e4*4);
  }
  __syncthreads();
  float wr[32];
  #pragma unroll
  for (int e = 0; e < 32; e++) wr[e] = wpL[t*32 + e];
  unsigned short md[32];
  #pragma unroll
  for (int d = 0; d < 32; d++){
    float a = 0.f;
    #pragma unroll
    for (int e = 0; e < 32; e++) a += wr[e] * kvL[d*32 + e];
    md[d] = f2bf(a);
  }
  unsigned short* dst = M + (size_t)b * 65536 + (size_t)t * DIM + h*32;
  #pragma unroll
  for (int q = 0; q < 4; q++) *(uint4*)(dst + q*8) = *(const uint4*)(md + q*8);
}

// ---------------- K4: out GEMM, FLIPPED operands (A=qn n-rows, B=M o-rows) ----------------
// D[row=quad*4+r -> n][col=t16 -> o]: per-lane 4 consecutive n => float4 epilogue, no bounce.
__global__ __launch_bounds__(512, 4) void k_out5(const unsigned short* __restrict__ M,
                                                 const unsigned short* __restrict__ qn,
                                                 const float* __restrict__ x,
                                                 const float* __restrict__ bproj,
                                                 float* __restrict__ out){
  __shared__ __align__(16) unsigned short As[8192];  // qn slabs (n rows)
  __shared__ __align__(16) unsigned short Bs[8192];  // M  slabs (o rows)
  const int t = threadIdx.x;
  const int w = t >> 6, l = t & 63;
  const int t16 = l & 15, quad = l >> 4;
  const int wm = w >> 1, wn = w & 1;     // wm 0..3 (n-quarter), wn 0..1 (o-half)
  // swizzle: 2 o-tiles sharing one (nt,b) within a 16-bid window
  const int bid = blockIdx.x;
  const int super = bid >> 4;
  const int rem = bid & 15;
  const int m = rem >> 3, lx = rem & 7;
  const int g = super * 8 + lx;          // 0..511
  const int nt = g >> 4, b = g & 15;
  const int o0 = m * 128, n0 = nt * 128;
  const unsigned short* A = qn + (size_t)b * NTOK * DIM;  // [n][256]
  const unsigned short* Bm = M + (size_t)b * 65536;       // [256][256]

  f32x4 acc[2][4];   // i over n (2x16), j over o (4x16)
  #pragma unroll
  for (int i = 0; i < 2; i++)
    #pragma unroll
    for (int j = 0; j < 4; j++){ acc[i][j][0]=0.f; acc[i][j][1]=0.f; acc[i][j][2]=0.f; acc[i][j][3]=0.f; }

  for (int k0 = 0; k0 < 256; k0 += 64){
    __syncthreads();
    #pragma unroll
    for (int s4 = 0; s4 < 4; s4++){
      int s = w * 4 + s4;            // 0..31
      int sl = s & 15;
      int tile = sl >> 1, kk = sl & 1;
      const unsigned short* src = (s < 16)
          ? (A  + (size_t)(n0 + tile*16 + t16) * DIM + k0 + kk*32 + quad*8)
          : (Bm + (size_t)(o0 + tile*16 + t16) * DIM + k0 + kk*32 + quad*8);
      gload_lds16(src, (s < 16) ? (As + sl * 512) : (Bs + sl * 512));
    }
    __syncthreads();
    #pragma unroll
    for (int kk = 0; kk < 2; kk++){
      short8 a[2], bb[4];
      #pragma unroll
      for (int i = 0; i < 2; i++) a[i]  = *(const short8*)(As + ((wm*2 + i)*2 + kk) * 512 + l * 8);
      #pragma unroll
      for (int j = 0; j < 4; j++) bb[j] = *(const short8*)(Bs + ((wn*4 + j)*2 + kk) * 512 + l * 8);
      #pragma unroll
      for (int i = 0; i < 2; i++)
        #pragma unroll
        for (int j = 0; j < 4; j++)
          acc[i][j] = __builtin_amdgcn_mfma_f32_16x16x32_bf16(a[i], bb[j], acc[i][j], 0, 0, 0);
    }
  }

  // epilogue: out[o][n] = acc + bias[o] + x[o][n], per-lane float4 along n
  const float* xb = x + (size_t)b * DIM * NTOK;
  float* ob = out + (size_t)b * DIM * NTOK;
  #pragma unroll
  for (int j = 0; j < 4; j++){
    int o = o0 + wn*64 + j*16 + t16;
    float bias = bproj[o];
    #pragma unroll
    for (int i = 0; i < 2; i++){
      int n = n0 + wm*32 + i*16 + quad*4;
      float4 xv = *(const float4*)(xb + (size_t)o * NTOK + n);
      float4 res = { acc[i][j][0] + bias + xv.x,
                     acc[i][j][1] + bias + xv.y,
                     acc[i][j][2] + bias + xv.z,
                     acc[i][j][3] + bias + xv.w };
      *(float4*)(ob + (size_t)o * NTOK + n) = res;
    }
  }
}

extern "C" void kernel_launch(void* const* d_in, const int* in_sizes, int n_in,
                              void* d_out, int out_size, void* d_ws, size_t ws_size,
                              hipStream_t stream){
  const float* x     = (const float*)d_in[0];
  const float* wqkv  = (const float*)d_in[1];
  const float* wproj = (const float*)d_in[2];
  const float* bproj = (const float*)d_in[3];
  float* out = (float*)d_out;
  char* ws = (char*)d_ws;

  // ws layout:
  unsigned short* xt   = (unsigned short*)(ws);                        // 32 MiB [b][n][256]
  unsigned short* qn   = (unsigned short*)(ws + ((size_t)32 << 20));   // 32 MiB [b][n][256]
  float* kvp           = (float*)(ws + ((size_t)64 << 20));            // 8 MiB [b][h][nt2 16][1024]
  unsigned short* M    = (unsigned short*)(ws + ((size_t)80 << 20));   // 2 MiB [b][256][256]
  unsigned short* wqbf = (unsigned short*)(ws + ((size_t)82 << 20));   // 384 KiB permuted

  k_transpose_x<<<dim3(64, 4, 16), 256, 0, stream>>>(x, xt);
  k_convert_w  <<<dim3(192), 256, 0, stream>>>(wqkv, wqbf);
  k_qkv6       <<<dim3(1536), 512, 0, stream>>>(wqbf, xt, qn, kvp);
  k_M          <<<dim3(8, 16), 256, 0, stream>>>(kvp, wproj, M);
  k_out5       <<<dim3(1024), 512, 0, stream>>>(M, qn, x, bproj, out);
}

// Round 3
// 235.877 us; speedup vs baseline: 1.0016x; 1.0016x over previous
//
#include <hip/hip_runtime.h>
#include <stdint.h>
#include <stddef.h>

#define DIM   256
#define NH    8
#define HD    32
#define BATCH 16
#define NTOK  4096   // 64*64

typedef __attribute__((ext_vector_type(8))) short short8;
typedef __attribute__((ext_vector_type(4))) float f32x4;

__device__ __forceinline__ unsigned short f2bf(float x){
  unsigned u = __float_as_uint(x);
  u += 0x7fffu + ((u >> 16) & 1u);       // RNE
  return (unsigned short)(u >> 16);
}
__device__ __forceinline__ float elu1(float v){
  return (v > 0.f) ? (v + 1.f) : __expf(v);
}
// async global->LDS, 16B per lane. lds dest = wave-uniform base + lane*16.
__device__ __forceinline__ void gload_lds16(const void* g, void* lds){
  __builtin_amdgcn_global_load_lds(
      (const __attribute__((address_space(1))) unsigned int*)g,
      (__attribute__((address_space(3))) unsigned int*)lds, 16, 0, 0);
}

// ---------------- P1: x [b][c][n] f32 -> x_t [b][n][c] bf16 ----------------
__global__ __launch_bounds__(256) void k_transpose_x(const float* __restrict__ x,
                                                     unsigned short* __restrict__ xt){
  __shared__ float tile[64][65];
  const int b = blockIdx.z, c0 = blockIdx.y * 64, n0 = blockIdx.x * 64;
  const float* xb = x + (size_t)b * DIM * NTOK;
  const int t = threadIdx.x;
  #pragma unroll
  for (int p = 0; p < 4; p++){
    int idx = t + p * 256;
    int row = idx >> 4;
    int col = (idx & 15) << 2;
    float4 v = *(const float4*)(xb + (size_t)(c0 + row) * NTOK + n0 + col);
    tile[row][col] = v.x; tile[row][col+1] = v.y; tile[row][col+2] = v.z; tile[row][col+3] = v.w;
  }
  __syncthreads();
  unsigned short* xtb = xt + (size_t)b * NTOK * DIM;
  #pragma unroll
  for (int p = 0; p < 4; p++){
    int idx = t + p * 256;
    int nl = idx >> 4;
    int cl = (idx & 15) << 2;
    ushort4 o;
    o.x = f2bf(tile[cl+0][nl]); o.y = f2bf(tile[cl+1][nl]);
    o.z = f2bf(tile[cl+2][nl]); o.w = f2bf(tile[cl+3][nl]);
    *(ushort4*)(xtb + (size_t)(n0 + nl) * DIM + c0 + cl) = o;
  }
}

// ---------------- P2: convert Wqkv to bf16, PERMUTED row layout ----------------
// dest rows: [0..255]=q. Then 4 tiles of 128: tile p = [k heads 2p,2p+1 | v heads 2p,2p+1]
__global__ __launch_bounds__(256) void k_convert_w(const float* __restrict__ wqkv,
                                                   unsigned short* __restrict__ wq_bf){
  int i = blockIdx.x * 256 + threadIdx.x;  // 49152 threads: 768 rows x 64 groups of 4c
  int row = i >> 6;
  int c4 = (i & 63) * 4;
  int dst;
  if (row < 256)      dst = row;
  else if (row < 512){ int p = (row - 256) >> 6; int s = (row - 256) & 63; dst = 256 + p*128 + s; }
  else               { int p = (row - 512) >> 6; int s = (row - 512) & 63; dst = 256 + p*128 + 64 + s; }
  float4 v = *(const float4*)(wqkv + (size_t)row * DIM + c4);
  ushort4 o = { f2bf(v.x), f2bf(v.y), f2bf(v.z), f2bf(v.w) };
  *(ushort4*)(wq_bf + (size_t)dst * DIM + c4) = o;
}

// ---------------- K1: persistent qkv GEMM — W-tile in registers, counted-vmcnt pipeline ----------------
// Same as k_qkv6, but register-pressure slimmed: only ONE B-fragment live at a time in the MFMA
// cluster (peak live ~110 regs < 128 cap at 16 waves/CU) -> no scratch spill.
__global__ __launch_bounds__(512, 4) void k_qkv7(const unsigned short* __restrict__ wbf,
                                                 const unsigned short* __restrict__ xt,
                                                 unsigned short* __restrict__ qn,
                                                 float* __restrict__ kvp){
  __shared__ __align__(16) unsigned short sh[33792];  // 32KB staging (2x 8192 u16) + 34KB bounce
  unsigned short* bsh = sh + 16384;                    // bounce: 128 x 136 u16
  const int t = threadIdx.x;
  const int w = t >> 6, l = t & 63;
  const int t16 = l & 15, quad = l >> 4;
  const int wm = w >> 1, wn = w & 1;     // wm 0..3 (o-quarter), wn 0..1 (n-half)
  // swizzle: 6 o-tiles sharing one chunk land on one XCD (48-bid window, bid%8 const per chunk)
  const int bid = blockIdx.x;
  const int super = bid / 48;            // 0..31
  const int rem = bid - super * 48;
  const int m = rem >> 3, lx = rem & 7;
  const int chunk = super * 8 + lx;      // 0..255
  const int b = chunk >> 4, nt2 = chunk & 15;
  const int o0 = m * 128;
  const bool isQ = (o0 < 256);
  const unsigned short* Bb = xt + ((size_t)b * NTOK + (size_t)nt2 * 256) * DIM;
  const int rowL = (w*16 + t16) * DIM + quad*8;   // per-lane staging offset (A and B share pattern)

  // ---- prologue: A-tile (128o x 256k) -> registers, staged through the B buffers ----
  short8 a_reg[4][2][2];   // [k0-chunk][i over o][kk]  = 64 VGPRs
  #pragma unroll
  for (int rp = 0; rp < 2; rp++){
    const unsigned short* srcA = wbf + (size_t)o0 * DIM + rowL + rp*128;
    gload_lds16(srcA,      sh +        (w*2+0)*512);
    gload_lds16(srcA + 32, sh +        (w*2+1)*512);
    gload_lds16(srcA + 64, sh + 8192 + (w*2+0)*512);
    gload_lds16(srcA + 96, sh + 8192 + (w*2+1)*512);
    asm volatile("s_waitcnt vmcnt(0)" ::: "memory");
    __builtin_amdgcn_s_barrier();
    #pragma unroll
    for (int cc = 0; cc < 2; cc++)
      #pragma unroll
      for (int i = 0; i < 2; i++)
        #pragma unroll
        for (int kk = 0; kk < 2; kk++)
          a_reg[rp*2+cc][i][kk] = *(const short8*)(sh + cc*8192 + ((wm*2+i)*2+kk)*512 + l*8);
    asm volatile("s_waitcnt lgkmcnt(0)" ::: "memory");   // reads retired before buffers reused
    __builtin_amdgcn_s_barrier();
  }

  // initial B stages: step0 (pair0,k0=0) -> buf0, step1 (pair0,k0=64) -> buf1
  gload_lds16(Bb + rowL,      sh +        (w*2+0)*512);
  gload_lds16(Bb + rowL + 32, sh +        (w*2+1)*512);
  gload_lds16(Bb + rowL + 64, sh + 8192 + (w*2+0)*512);
  gload_lds16(Bb + rowL + 96, sh + 8192 + (w*2+1)*512);

  f32x4 acc[2][4];
  #pragma unroll
  for (int i = 0; i < 2; i++)
    #pragma unroll
    for (int j = 0; j < 4; j++){ acc[i][j][0]=0.f; acc[i][j][1]=0.f; acc[i][j][2]=0.f; acc[i][j][3]=0.f; }
  f32x4 kvacc;
  kvacc[0]=0.f; kvacc[1]=0.f; kvacc[2]=0.f; kvacc[3]=0.f;

  // ---- main pipeline: 8 steps = 2 pairs x 4 K-steps, depth-2 prefetch ----
  #pragma unroll
  for (int s = 0; s < 8; s++){
    if (s < 7) { asm volatile("s_waitcnt vmcnt(2)" ::: "memory"); }  // own STAGE(s+1) may stay in flight
    else       { asm volatile("s_waitcnt vmcnt(0)" ::: "memory"); }
    __builtin_amdgcn_s_barrier();                                    // all waves' STAGE(s) complete
    const unsigned short* bufc = sh + (s & 1) * 8192;
    #pragma unroll
    for (int kk = 0; kk < 2; kk++){
      #pragma unroll
      for (int j = 0; j < 4; j++){
        short8 bbj = *(const short8*)(bufc + ((wn*4+j)*2+kk)*512 + l*8);  // 1 B-frag live
        #pragma unroll
        for (int i = 0; i < 2; i++)
          acc[i][j] = __builtin_amdgcn_mfma_f32_16x16x32_bf16(a_reg[s&3][i][kk], bbj, acc[i][j], 0, 0, 0);
      }
    }
    __builtin_amdgcn_s_barrier();       // all waves consumed buf[s&1] (MFMA forces lgkm wait)
    if (s < 6){                          // prefetch step s+2 into the buffer just freed
      const int s2 = s + 2;
      const unsigned short* src = Bb + (size_t)((s2 >> 2) * 128) * DIM + rowL + (s2 & 3) * 64;
      unsigned short* db = sh + (s & 1) * 8192;
      gload_lds16(src,      db + (w*2+0)*512);
      gload_lds16(src + 32, db + (w*2+1)*512);
    }
    if ((s & 3) == 3){
      // ---- per-pair epilogue (overlaps in-flight stages for the next pair) ----
      const int n0 = (nt2*2 + (s >> 2)) * 128;
      if (isQ || wm < 2){
        #pragma unroll
        for (int i = 0; i < 2; i++)
          #pragma unroll
          for (int j = 0; j < 4; j++)
            #pragma unroll
            for (int r = 0; r < 4; r++) acc[i][j][r] = elu1(acc[i][j][r]);
        float sc[4];
        #pragma unroll
        for (int j = 0; j < 4; j++){
          float v = 0.f;
          #pragma unroll
          for (int i = 0; i < 2; i++)
            #pragma unroll
            for (int r = 0; r < 4; r++) v += acc[i][j][r];
          v += __shfl_xor(v, 16);
          v += __shfl_xor(v, 32);
          sc[j] = 1.0f / v;
        }
        #pragma unroll
        for (int i = 0; i < 2; i++)
          #pragma unroll
          for (int j = 0; j < 4; j++){
            float inv = sc[j];
            #pragma unroll
            for (int r = 0; r < 4; r++) acc[i][j][r] *= inv;
          }
      }
      if (isQ){
        // bounce [n_l][o_l] stride 136, packed b64
        #pragma unroll
        for (int i = 0; i < 2; i++)
          #pragma unroll
          for (int j = 0; j < 4; j++){
            int n_l = wn*64 + j*16 + t16;
            int o_l0 = wm*32 + i*16 + quad*4;
            ushort4 pk = { f2bf(acc[i][j][0]), f2bf(acc[i][j][1]),
                           f2bf(acc[i][j][2]), f2bf(acc[i][j][3]) };
            *(ushort4*)(bsh + n_l*136 + o_l0) = pk;
          }
        asm volatile("s_waitcnt lgkmcnt(0)" ::: "memory");   // LDS writes visible (no vmcnt drain!)
        __builtin_amdgcn_s_barrier();
        unsigned short* dst = qn + (size_t)b * NTOK * DIM;
        #pragma unroll
        for (int p2 = 0; p2 < 4; p2++){
          int gg = t + p2 * 512;
          int n_l = gg >> 4, c = gg & 15;
          uint4 v = *(const uint4*)(bsh + n_l*136 + c*8);
          *(uint4*)(dst + (size_t)(n0 + n_l) * DIM + o0 + c*8) = v;
        }
      } else {
        // bounce [o_l][n_l] stride 136 (K-contiguous along n for the kv MFMA)
        #pragma unroll
        for (int i = 0; i < 2; i++)
          #pragma unroll
          for (int j = 0; j < 4; j++){
            int n_l = wn*64 + j*16 + t16;
            #pragma unroll
            for (int r = 0; r < 4; r++){
              int o_l = wm*32 + i*16 + quad*4 + r;
              bsh[o_l*136 + n_l] = f2bf(acc[i][j][r]);
            }
          }
        asm volatile("s_waitcnt lgkmcnt(0)" ::: "memory");
        __builtin_amdgcn_s_barrier();
        // kv partial over this pair's 128 tokens, accumulated in registers across pairs
        const int hl = w >> 2, dh = (w >> 1) & 1, eh = w & 1;
        const unsigned short* kbase = bsh + (hl*32 + dh*16) * 136;        // normalized k rows
        const unsigned short* vbase = bsh + (64 + hl*32 + eh*16) * 136;   // raw v rows
        #pragma unroll
        for (int kk2 = 0; kk2 < 4; kk2++){
          int nn = kk2*32 + quad*8;
          short8 afrag = *(const short8*)(kbase + t16*136 + nn);
          short8 bfrag = *(const short8*)(vbase + t16*136 + nn);
          kvacc = __builtin_amdgcn_mfma_f32_16x16x32_bf16(afrag, bfrag, kvacc, 0, 0, 0);
        }
      }
      if (s == 3){
        #pragma unroll
        for (int i = 0; i < 2; i++)
          #pragma unroll
          for (int j = 0; j < 4; j++){ acc[i][j][0]=0.f; acc[i][j][1]=0.f; acc[i][j][2]=0.f; acc[i][j][3]=0.f; }
      }
    }
  }

  if (!isQ){
    const int pp = (o0 >> 7) - 2;          // head pair 0..3
    const int hl = w >> 2, dh = (w >> 1) & 1, eh = w & 1;
    float* dst = kvp + ((size_t)((b*8 + pp*2 + hl) * 16 + nt2)) * 1024;
    #pragma unroll
    for (int r = 0; r < 4; r++)
      dst[(dh*16 + quad*4 + r)*32 + eh*16 + t16] = kvacc[r];
  }
}

// ---------------- K3: reduce kv partials + fold Wproj: M[b][o][h*32+d] = sum_e Wp[o][h*32+e]*kv[d][e]
__global__ __launch_bounds__(256) void k_M(const float* __restrict__ kvp,
                                           const float* __restrict__ wproj,
                                           unsigned short* __restrict__ M){
  __shared__ float kvL[1024];
  __shared__ float wpL[8192];   // [o][e] 256x32
  const int t = threadIdx.x;
  const int h = blockIdx.x, b = blockIdx.y;
  const float* pbase = kvp + (size_t)((b*8 + h) * 16) * 1024;
  {
    float4 a = {0.f,0.f,0.f,0.f};
    #pragma unroll
    for (int p = 0; p < 16; p++){
      float4 v = *(const float4*)(pbase + (size_t)p*1024 + t*4);
      a.x += v.x; a.y += v.y; a.z += v.z; a.w += v.w;
    }
    *(float4*)(kvL + t*4) = a;
  }
  #pragma unroll
  for (int p = 0; p < 8; p++){
    int idx = t + p * 256;          // float4 index over 256x32
    int o = idx >> 3, e4 = idx & 7;
    *(float4*)(wpL + o*32 + e4*4) = *(const float4*)(wproj + (size_t)o * DIM + h*32 + e4*4);
  }
  __syncthreads();
  float wr[32];
  #pragma unroll
  for (int e = 0; e < 32; e++) wr[e] = wpL[t*32 + e];
  unsigned short md[32];
  #pragma unroll
  for (int d = 0; d < 32; d++){
    float a = 0.f;
    #pragma unroll
    for (int e = 0; e < 32; e++) a += wr[e] * kvL[d*32 + e];
    md[d] = f2bf(a);
  }
  unsigned short* dst = M + (size_t)b * 65536 + (size_t)t * DIM + h*32;
  #pragma unroll
  for (int q = 0; q < 4; q++) *(uint4*)(dst + q*8) = *(const uint4*)(md + q*8);
}

// ---------------- K4: out GEMM, FLIPPED operands (A=qn n-rows, B=M o-rows) ----------------
// D[row=quad*4+r -> n][col=t16 -> o]: per-lane 4 consecutive n => float4 epilogue, no bounce.
__global__ __launch_bounds__(512, 4) void k_out5(const unsigned short* __restrict__ M,
                                                 const unsigned short* __restrict__ qn,
                                                 const float* __restrict__ x,
                                                 const float* __restrict__ bproj,
                                                 float* __restrict__ out){
  __shared__ __align__(16) unsigned short As[8192];  // qn slabs (n rows)
  __shared__ __align__(16) unsigned short Bs[8192];  // M  slabs (o rows)
  const int t = threadIdx.x;
  const int w = t >> 6, l = t & 63;
  const int t16 = l & 15, quad = l >> 4;
  const int wm = w >> 1, wn = w & 1;     // wm 0..3 (n-quarter), wn 0..1 (o-half)
  // swizzle: 2 o-tiles sharing one (nt,b) within a 16-bid window
  const int bid = blockIdx.x;
  const int super = bid >> 4;
  const int rem = bid & 15;
  const int m = rem >> 3, lx = rem & 7;
  const int g = super * 8 + lx;          // 0..511
  const int nt = g >> 4, b = g & 15;
  const int o0 = m * 128, n0 = nt * 128;
  const unsigned short* A = qn + (size_t)b * NTOK * DIM;  // [n][256]
  const unsigned short* Bm = M + (size_t)b * 65536;       // [256][256]

  f32x4 acc[2][4];   // i over n (2x16), j over o (4x16)
  #pragma unroll
  for (int i = 0; i < 2; i++)
    #pragma unroll
    for (int j = 0; j < 4; j++){ acc[i][j][0]=0.f; acc[i][j][1]=0.f; acc[i][j][2]=0.f; acc[i][j][3]=0.f; }

  for (int k0 = 0; k0 < 256; k0 += 64){
    __syncthreads();
    #pragma unroll
    for (int s4 = 0; s4 < 4; s4++){
      int s = w * 4 + s4;            // 0..31
      int sl = s & 15;
      int tile = sl >> 1, kk = sl & 1;
      const unsigned short* src = (s < 16)
          ? (A  + (size_t)(n0 + tile*16 + t16) * DIM + k0 + kk*32 + quad*8)
          : (Bm + (size_t)(o0 + tile*16 + t16) * DIM + k0 + kk*32 + quad*8);
      gload_lds16(src, (s < 16) ? (As + sl * 512) : (Bs + sl * 512));
    }
    __syncthreads();
    #pragma unroll
    for (int kk = 0; kk < 2; kk++){
      short8 a[2], bb[4];
      #pragma unroll
      for (int i = 0; i < 2; i++) a[i]  = *(const short8*)(As + ((wm*2 + i)*2 + kk) * 512 + l * 8);
      #pragma unroll
      for (int j = 0; j < 4; j++) bb[j] = *(const short8*)(Bs + ((wn*4 + j)*2 + kk) * 512 + l * 8);
      #pragma unroll
      for (int i = 0; i < 2; i++)
        #pragma unroll
        for (int j = 0; j < 4; j++)
          acc[i][j] = __builtin_amdgcn_mfma_f32_16x16x32_bf16(a[i], bb[j], acc[i][j], 0, 0, 0);
    }
  }

  // epilogue: out[o][n] = acc + bias[o] + x[o][n], per-lane float4 along n
  const float* xb = x + (size_t)b * DIM * NTOK;
  float* ob = out + (size_t)b * DIM * NTOK;
  #pragma unroll
  for (int j = 0; j < 4; j++){
    int o = o0 + wn*64 + j*16 + t16;
    float bias = bproj[o];
    #pragma unroll
    for (int i = 0; i < 2; i++){
      int n = n0 + wm*32 + i*16 + quad*4;
      float4 xv = *(const float4*)(xb + (size_t)o * NTOK + n);
      float4 res = { acc[i][j][0] + bias + xv.x,
                     acc[i][j][1] + bias + xv.y,
                     acc[i][j][2] + bias + xv.z,
                     acc[i][j][3] + bias + xv.w };
      *(float4*)(ob + (size_t)o * NTOK + n) = res;
    }
  }
}

extern "C" void kernel_launch(void* const* d_in, const int* in_sizes, int n_in,
                              void* d_out, int out_size, void* d_ws, size_t ws_size,
                              hipStream_t stream){
  const float* x     = (const float*)d_in[0];
  const float* wqkv  = (const float*)d_in[1];
  const float* wproj = (const float*)d_in[2];
  const float* bproj = (const float*)d_in[3];
  float* out = (float*)d_out;
  char* ws = (char*)d_ws;

  // ws layout:
  unsigned short* xt   = (unsigned short*)(ws);                        // 32 MiB [b][n][256]
  unsigned short* qn   = (unsigned short*)(ws + ((size_t)32 << 20));   // 32 MiB [b][n][256]
  float* kvp           = (float*)(ws + ((size_t)64 << 20));            // 8 MiB [b][h][nt2 16][1024]
  unsigned short* M    = (unsigned short*)(ws + ((size_t)80 << 20));   // 2 MiB [b][256][256]
  unsigned short* wqbf = (unsigned short*)(ws + ((size_t)82 << 20));   // 384 KiB permuted

  k_transpose_x<<<dim3(64, 4, 16), 256, 0, stream>>>(x, xt);
  k_convert_w  <<<dim3(192), 256, 0, stream>>>(wqkv, wqbf);
  k_qkv7       <<<dim3(1536), 512, 0, stream>>>(wqbf, xt, qn, kvp);
  k_M          <<<dim3(8, 16), 256, 0, stream>>>(kvp, wproj, M);
  k_out5       <<<dim3(1024), 512, 0, stream>>>(M, qn, x, bproj, out);
}

// Round 4
// 224.659 us; speedup vs baseline: 1.0516x; 1.0499x over previous
//
#include <hip/hip_runtime.h>
#include <stdint.h>
#include <stddef.h>

#define DIM   256
#define NH    8
#define HD    32
#define BATCH 16
#define NTOK  4096   // 64*64

typedef __attribute__((ext_vector_type(8))) short short8;
typedef __attribute__((ext_vector_type(4))) float f32x4;

__device__ __forceinline__ unsigned short f2bf(float x){
  unsigned u = __float_as_uint(x);
  u += 0x7fffu + ((u >> 16) & 1u);       // RNE
  return (unsigned short)(u >> 16);
}
__device__ __forceinline__ float elu1(float v){
  return (v > 0.f) ? (v + 1.f) : __expf(v);
}
// async global->LDS, 16B per lane. lds dest = wave-uniform base + lane*16.
__device__ __forceinline__ void gload_lds16(const void* g, void* lds){
  __builtin_amdgcn_global_load_lds(
      (const __attribute__((address_space(1))) unsigned int*)g,
      (__attribute__((address_space(3))) unsigned int*)lds, 16, 0, 0);
}

// ---------------- P1: x [b][c][n] f32 -> x_t [b][n][c] bf16 ----------------
__global__ __launch_bounds__(256) void k_transpose_x(const float* __restrict__ x,
                                                     unsigned short* __restrict__ xt){
  __shared__ float tile[64][65];
  const int b = blockIdx.z, c0 = blockIdx.y * 64, n0 = blockIdx.x * 64;
  const float* xb = x + (size_t)b * DIM * NTOK;
  const int t = threadIdx.x;
  #pragma unroll
  for (int p = 0; p < 4; p++){
    int idx = t + p * 256;
    int row = idx >> 4;
    int col = (idx & 15) << 2;
    float4 v = *(const float4*)(xb + (size_t)(c0 + row) * NTOK + n0 + col);
    tile[row][col] = v.x; tile[row][col+1] = v.y; tile[row][col+2] = v.z; tile[row][col+3] = v.w;
  }
  __syncthreads();
  unsigned short* xtb = xt + (size_t)b * NTOK * DIM;
  #pragma unroll
  for (int p = 0; p < 4; p++){
    int idx = t + p * 256;
    int nl = idx >> 4;
    int cl = (idx & 15) << 2;
    ushort4 o;
    o.x = f2bf(tile[cl+0][nl]); o.y = f2bf(tile[cl+1][nl]);
    o.z = f2bf(tile[cl+2][nl]); o.w = f2bf(tile[cl+3][nl]);
    *(ushort4*)(xtb + (size_t)(n0 + nl) * DIM + c0 + cl) = o;
  }
}

// ---------------- P2: convert Wqkv to bf16, PERMUTED row layout ----------------
// dest rows: [0..255]=q. Then 4 tiles of 128: tile p = [k heads 2p,2p+1 | v heads 2p,2p+1]
__global__ __launch_bounds__(256) void k_convert_w(const float* __restrict__ wqkv,
                                                   unsigned short* __restrict__ wq_bf){
  int i = blockIdx.x * 256 + threadIdx.x;  // 49152 threads: 768 rows x 64 groups of 4c
  int row = i >> 6;
  int c4 = (i & 63) * 4;
  int dst;
  if (row < 256)      dst = row;
  else if (row < 512){ int p = (row - 256) >> 6; int s = (row - 256) & 63; dst = 256 + p*128 + s; }
  else               { int p = (row - 512) >> 6; int s = (row - 512) & 63; dst = 256 + p*128 + 64 + s; }
  float4 v = *(const float4*)(wqkv + (size_t)row * DIM + c4);
  ushort4 o = { f2bf(v.x), f2bf(v.y), f2bf(v.z), f2bf(v.w) };
  *(ushort4*)(wq_bf + (size_t)dst * DIM + c4) = o;
}

// ---------------- K1: persistent qkv GEMM — W-tile in registers, counted-vmcnt pipeline ----------------
// Same structure as k_qkv7, but __launch_bounds__(512,1): allocator may use up to 512 VGPRs ->
// a_reg (64) + acc (36 AGPR) + epilogue temps fit WITHOUT scratch spill. 1 block/CU (8 waves,
// HK-style low-occupancy deep pipeline) instead of 2 spilling blocks.
__global__ __launch_bounds__(512, 1) void k_qkv8(const unsigned short* __restrict__ wbf,
                                                 const unsigned short* __restrict__ xt,
                                                 unsigned short* __restrict__ qn,
                                                 float* __restrict__ kvp){
  __shared__ __align__(16) unsigned short sh[33792];  // 32KB staging (2x 8192 u16) + 34KB bounce
  unsigned short* bsh = sh + 16384;                    // bounce: 128 x 136 u16
  const int t = threadIdx.x;
  const int w = t >> 6, l = t & 63;
  const int t16 = l & 15, quad = l >> 4;
  const int wm = w >> 1, wn = w & 1;     // wm 0..3 (o-quarter), wn 0..1 (n-half)
  // swizzle: 6 o-tiles sharing one chunk land on one XCD (48-bid window, bid%8 const per chunk)
  const int bid = blockIdx.x;
  const int super = bid / 48;            // 0..31
  const int rem = bid - super * 48;
  const int m = rem >> 3, lx = rem & 7;
  const int chunk = super * 8 + lx;      // 0..255
  const int b = chunk >> 4, nt2 = chunk & 15;
  const int o0 = m * 128;
  const bool isQ = (o0 < 256);
  const unsigned short* Bb = xt + ((size_t)b * NTOK + (size_t)nt2 * 256) * DIM;
  const int rowL = (w*16 + t16) * DIM + quad*8;   // per-lane staging offset (A and B share pattern)

  // ---- prologue: A-tile (128o x 256k) -> registers, staged through the B buffers ----
  short8 a_reg[4][2][2];   // [k0-chunk][i over o][kk]  = 64 VGPRs
  #pragma unroll
  for (int rp = 0; rp < 2; rp++){
    const unsigned short* srcA = wbf + (size_t)o0 * DIM + rowL + rp*128;
    gload_lds16(srcA,      sh +        (w*2+0)*512);
    gload_lds16(srcA + 32, sh +        (w*2+1)*512);
    gload_lds16(srcA + 64, sh + 8192 + (w*2+0)*512);
    gload_lds16(srcA + 96, sh + 8192 + (w*2+1)*512);
    asm volatile("s_waitcnt vmcnt(0)" ::: "memory");
    __builtin_amdgcn_s_barrier();
    #pragma unroll
    for (int cc = 0; cc < 2; cc++)
      #pragma unroll
      for (int i = 0; i < 2; i++)
        #pragma unroll
        for (int kk = 0; kk < 2; kk++)
          a_reg[rp*2+cc][i][kk] = *(const short8*)(sh + cc*8192 + ((wm*2+i)*2+kk)*512 + l*8);
    asm volatile("s_waitcnt lgkmcnt(0)" ::: "memory");   // reads retired before buffers reused
    __builtin_amdgcn_s_barrier();
  }

  // initial B stages: step0 (pair0,k0=0) -> buf0, step1 (pair0,k0=64) -> buf1
  gload_lds16(Bb + rowL,      sh +        (w*2+0)*512);
  gload_lds16(Bb + rowL + 32, sh +        (w*2+1)*512);
  gload_lds16(Bb + rowL + 64, sh + 8192 + (w*2+0)*512);
  gload_lds16(Bb + rowL + 96, sh + 8192 + (w*2+1)*512);

  f32x4 acc[2][4];
  #pragma unroll
  for (int i = 0; i < 2; i++)
    #pragma unroll
    for (int j = 0; j < 4; j++){ acc[i][j][0]=0.f; acc[i][j][1]=0.f; acc[i][j][2]=0.f; acc[i][j][3]=0.f; }
  f32x4 kvacc;
  kvacc[0]=0.f; kvacc[1]=0.f; kvacc[2]=0.f; kvacc[3]=0.f;

  // ---- main pipeline: 8 steps = 2 pairs x 4 K-steps, depth-2 prefetch ----
  #pragma unroll
  for (int s = 0; s < 8; s++){
    if (s < 7) { asm volatile("s_waitcnt vmcnt(2)" ::: "memory"); }  // own STAGE(s+1) may stay in flight
    else       { asm volatile("s_waitcnt vmcnt(0)" ::: "memory"); }
    __builtin_amdgcn_s_barrier();                                    // all waves' STAGE(s) complete
    const unsigned short* bufc = sh + (s & 1) * 8192;
    #pragma unroll
    for (int kk = 0; kk < 2; kk++){
      short8 bb[4];
      #pragma unroll
      for (int j = 0; j < 4; j++) bb[j] = *(const short8*)(bufc + ((wn*4+j)*2+kk)*512 + l*8);
      #pragma unroll
      for (int i = 0; i < 2; i++)
        #pragma unroll
        for (int j = 0; j < 4; j++)
          acc[i][j] = __builtin_amdgcn_mfma_f32_16x16x32_bf16(a_reg[s&3][i][kk], bb[j], acc[i][j], 0, 0, 0);
    }
    __builtin_amdgcn_s_barrier();       // all waves consumed buf[s&1] (MFMA forces lgkm wait)
    if (s < 6){                          // prefetch step s+2 into the buffer just freed
      const int s2 = s + 2;
      const unsigned short* src = Bb + (size_t)((s2 >> 2) * 128) * DIM + rowL + (s2 & 3) * 64;
      unsigned short* db = sh + (s & 1) * 8192;
      gload_lds16(src,      db + (w*2+0)*512);
      gload_lds16(src + 32, db + (w*2+1)*512);
    }
    if ((s & 3) == 3){
      // ---- per-pair epilogue (overlaps in-flight stages for the next pair) ----
      const int n0 = (nt2*2 + (s >> 2)) * 128;
      if (isQ || wm < 2){
        #pragma unroll
        for (int i = 0; i < 2; i++)
          #pragma unroll
          for (int j = 0; j < 4; j++)
            #pragma unroll
            for (int r = 0; r < 4; r++) acc[i][j][r] = elu1(acc[i][j][r]);
        float sc[4];
        #pragma unroll
        for (int j = 0; j < 4; j++){
          float v = 0.f;
          #pragma unroll
          for (int i = 0; i < 2; i++)
            #pragma unroll
            for (int r = 0; r < 4; r++) v += acc[i][j][r];
          v += __shfl_xor(v, 16);
          v += __shfl_xor(v, 32);
          sc[j] = 1.0f / v;
        }
        #pragma unroll
        for (int i = 0; i < 2; i++)
          #pragma unroll
          for (int j = 0; j < 4; j++){
            float inv = sc[j];
            #pragma unroll
            for (int r = 0; r < 4; r++) acc[i][j][r] *= inv;
          }
      }
      if (isQ){
        // bounce [n_l][o_l] stride 136, packed b64
        #pragma unroll
        for (int i = 0; i < 2; i++)
          #pragma unroll
          for (int j = 0; j < 4; j++){
            int n_l = wn*64 + j*16 + t16;
            int o_l0 = wm*32 + i*16 + quad*4;
            ushort4 pk = { f2bf(acc[i][j][0]), f2bf(acc[i][j][1]),
                           f2bf(acc[i][j][2]), f2bf(acc[i][j][3]) };
            *(ushort4*)(bsh + n_l*136 + o_l0) = pk;
          }
        asm volatile("s_waitcnt lgkmcnt(0)" ::: "memory");   // LDS writes visible (no vmcnt drain!)
        __builtin_amdgcn_s_barrier();
        unsigned short* dst = qn + (size_t)b * NTOK * DIM;
        #pragma unroll
        for (int p2 = 0; p2 < 4; p2++){
          int gg = t + p2 * 512;
          int n_l = gg >> 4, c = gg & 15;
          uint4 v = *(const uint4*)(bsh + n_l*136 + c*8);
          *(uint4*)(dst + (size_t)(n0 + n_l) * DIM + o0 + c*8) = v;
        }
      } else {
        // bounce [o_l][n_l] stride 136 (K-contiguous along n for the kv MFMA)
        #pragma unroll
        for (int i = 0; i < 2; i++)
          #pragma unroll
          for (int j = 0; j < 4; j++){
            int n_l = wn*64 + j*16 + t16;
            #pragma unroll
            for (int r = 0; r < 4; r++){
              int o_l = wm*32 + i*16 + quad*4 + r;
              bsh[o_l*136 + n_l] = f2bf(acc[i][j][r]);
            }
          }
        asm volatile("s_waitcnt lgkmcnt(0)" ::: "memory");
        __builtin_amdgcn_s_barrier();
        // kv partial over this pair's 128 tokens, accumulated in registers across pairs
        const int hl = w >> 2, dh = (w >> 1) & 1, eh = w & 1;
        const unsigned short* kbase = bsh + (hl*32 + dh*16) * 136;        // normalized k rows
        const unsigned short* vbase = bsh + (64 + hl*32 + eh*16) * 136;   // raw v rows
        #pragma unroll
        for (int kk2 = 0; kk2 < 4; kk2++){
          int nn = kk2*32 + quad*8;
          short8 afrag = *(const short8*)(kbase + t16*136 + nn);
          short8 bfrag = *(const short8*)(vbase + t16*136 + nn);
          kvacc = __builtin_amdgcn_mfma_f32_16x16x32_bf16(afrag, bfrag, kvacc, 0, 0, 0);
        }
      }
      if (s == 3){
        #pragma unroll
        for (int i = 0; i < 2; i++)
          #pragma unroll
          for (int j = 0; j < 4; j++){ acc[i][j][0]=0.f; acc[i][j][1]=0.f; acc[i][j][2]=0.f; acc[i][j][3]=0.f; }
      }
    }
  }

  if (!isQ){
    const int pp = (o0 >> 7) - 2;          // head pair 0..3
    const int hl = w >> 2, dh = (w >> 1) & 1, eh = w & 1;
    float* dst = kvp + ((size_t)((b*8 + pp*2 + hl) * 16 + nt2)) * 1024;
    #pragma unroll
    for (int r = 0; r < 4; r++)
      dst[(dh*16 + quad*4 + r)*32 + eh*16 + t16] = kvacc[r];
  }
}

// ---------------- K3: reduce kv partials + fold Wproj: M[b][o][h*32+d] = sum_e Wp[o][h*32+e]*kv[d][e]
__global__ __launch_bounds__(256) void k_M(const float* __restrict__ kvp,
                                           const float* __restrict__ wproj,
                                           unsigned short* __restrict__ M){
  __shared__ float kvL[1024];
  __shared__ float wpL[8192];   // [o][e] 256x32
  const int t = threadIdx.x;
  const int h = blockIdx.x, b = blockIdx.y;
  const float* pbase = kvp + (size_t)((b*8 + h) * 16) * 1024;
  {
    float4 a = {0.f,0.f,0.f,0.f};
    #pragma unroll
    for (int p = 0; p < 16; p++){
      float4 v = *(const float4*)(pbase + (size_t)p*1024 + t*4);
      a.x += v.x; a.y += v.y; a.z += v.z; a.w += v.w;
    }
    *(float4*)(kvL + t*4) = a;
  }
  #pragma unroll
  for (int p = 0; p < 8; p++){
    int idx = t + p * 256;          // float4 index over 256x32
    int o = idx >> 3, e4 = idx & 7;
    *(float4*)(wpL + o*32 + e4*4) = *(const float4*)(wproj + (size_t)o * DIM + h*32 + e4*4);
  }
  __syncthreads();
  float wr[32];
  #pragma unroll
  for (int e = 0; e < 32; e++) wr[e] = wpL[t*32 + e];
  unsigned short md[32];
  #pragma unroll
  for (int d = 0; d < 32; d++){
    float a = 0.f;
    #pragma unroll
    for (int e = 0; e < 32; e++) a += wr[e] * kvL[d*32 + e];
    md[d] = f2bf(a);
  }
  unsigned short* dst = M + (size_t)b * 65536 + (size_t)t * DIM + h*32;
  #pragma unroll
  for (int q = 0; q < 4; q++) *(uint4*)(dst + q*8) = *(const uint4*)(md + q*8);
}

// ---------------- K4: out GEMM, FLIPPED operands (A=qn n-rows, B=M o-rows) ----------------
// D[row=quad*4+r -> n][col=t16 -> o]: per-lane 4 consecutive n => float4 epilogue, no bounce.
__global__ __launch_bounds__(512, 4) void k_out5(const unsigned short* __restrict__ M,
                                                 const unsigned short* __restrict__ qn,
                                                 const float* __restrict__ x,
                                                 const float* __restrict__ bproj,
                                                 float* __restrict__ out){
  __shared__ __align__(16) unsigned short As[8192];  // qn slabs (n rows)
  __shared__ __align__(16) unsigned short Bs[8192];  // M  slabs (o rows)
  const int t = threadIdx.x;
  const int w = t >> 6, l = t & 63;
  const int t16 = l & 15, quad = l >> 4;
  const int wm = w >> 1, wn = w & 1;     // wm 0..3 (n-quarter), wn 0..1 (o-half)
  // swizzle: 2 o-tiles sharing one (nt,b) within a 16-bid window
  const int bid = blockIdx.x;
  const int super = bid >> 4;
  const int rem = bid & 15;
  const int m = rem >> 3, lx = rem & 7;
  const int g = super * 8 + lx;          // 0..511
  const int nt = g >> 4, b = g & 15;
  const int o0 = m * 128, n0 = nt * 128;
  const unsigned short* A = qn + (size_t)b * NTOK * DIM;  // [n][256]
  const unsigned short* Bm = M + (size_t)b * 65536;       // [256][256]

  f32x4 acc[2][4];   // i over n (2x16), j over o (4x16)
  #pragma unroll
  for (int i = 0; i < 2; i++)
    #pragma unroll
    for (int j = 0; j < 4; j++){ acc[i][j][0]=0.f; acc[i][j][1]=0.f; acc[i][j][2]=0.f; acc[i][j][3]=0.f; }

  for (int k0 = 0; k0 < 256; k0 += 64){
    __syncthreads();
    #pragma unroll
    for (int s4 = 0; s4 < 4; s4++){
      int s = w * 4 + s4;            // 0..31
      int sl = s & 15;
      int tile = sl >> 1, kk = sl & 1;
      const unsigned short* src = (s < 16)
          ? (A  + (size_t)(n0 + tile*16 + t16) * DIM + k0 + kk*32 + quad*8)
          : (Bm + (size_t)(o0 + tile*16 + t16) * DIM + k0 + kk*32 + quad*8);
      gload_lds16(src, (s < 16) ? (As + sl * 512) : (Bs + sl * 512));
    }
    __syncthreads();
    #pragma unroll
    for (int kk = 0; kk < 2; kk++){
      short8 a[2], bb[4];
      #pragma unroll
      for (int i = 0; i < 2; i++) a[i]  = *(const short8*)(As + ((wm*2 + i)*2 + kk) * 512 + l * 8);
      #pragma unroll
      for (int j = 0; j < 4; j++) bb[j] = *(const short8*)(Bs + ((wn*4 + j)*2 + kk) * 512 + l * 8);
      #pragma unroll
      for (int i = 0; i < 2; i++)
        #pragma unroll
        for (int j = 0; j < 4; j++)
          acc[i][j] = __builtin_amdgcn_mfma_f32_16x16x32_bf16(a[i], bb[j], acc[i][j], 0, 0, 0);
    }
  }

  // epilogue: out[o][n] = acc + bias[o] + x[o][n], per-lane float4 along n
  const float* xb = x + (size_t)b * DIM * NTOK;
  float* ob = out + (size_t)b * DIM * NTOK;
  #pragma unroll
  for (int j = 0; j < 4; j++){
    int o = o0 + wn*64 + j*16 + t16;
    float bias = bproj[o];
    #pragma unroll
    for (int i = 0; i < 2; i++){
      int n = n0 + wm*32 + i*16 + quad*4;
      float4 xv = *(const float4*)(xb + (size_t)o * NTOK + n);
      float4 res = { acc[i][j][0] + bias + xv.x,
                     acc[i][j][1] + bias + xv.y,
                     acc[i][j][2] + bias + xv.z,
                     acc[i][j][3] + bias + xv.w };
      *(float4*)(ob + (size_t)o * NTOK + n) = res;
    }
  }
}

extern "C" void kernel_launch(void* const* d_in, const int* in_sizes, int n_in,
                              void* d_out, int out_size, void* d_ws, size_t ws_size,
                              hipStream_t stream){
  const float* x     = (const float*)d_in[0];
  const float* wqkv  = (const float*)d_in[1];
  const float* wproj = (const float*)d_in[2];
  const float* bproj = (const float*)d_in[3];
  float* out = (float*)d_out;
  char* ws = (char*)d_ws;

  // ws layout:
  unsigned short* xt   = (unsigned short*)(ws);                        // 32 MiB [b][n][256]
  unsigned short* qn   = (unsigned short*)(ws + ((size_t)32 << 20));   // 32 MiB [b][n][256]
  float* kvp           = (float*)(ws + ((size_t)64 << 20));            // 8 MiB [b][h][nt2 16][1024]
  unsigned short* M    = (unsigned short*)(ws + ((size_t)80 << 20));   // 2 MiB [b][256][256]
  unsigned short* wqbf = (unsigned short*)(ws + ((size_t)82 << 20));   // 384 KiB permuted

  k_transpose_x<<<dim3(64, 4, 16), 256, 0, stream>>>(x, xt);
  k_convert_w  <<<dim3(192), 256, 0, stream>>>(wqkv, wqbf);
  k_qkv8       <<<dim3(1536), 512, 0, stream>>>(wqbf, xt, qn, kvp);
  k_M          <<<dim3(8, 16), 256, 0, stream>>>(kvp, wproj, M);
  k_out5       <<<dim3(1024), 512, 0, stream>>>(M, qn, x, bproj, out);
}